// Round 5
// baseline (382.818 us; speedup 1.0000x reference)
//
#include <hip/hip_runtime.h>

#define NB 8      // NUM_BLOCK
#define NT 500    // NUM_FRAME
#define NF 257    // NUM_BIN
#define NC 8      // NUM_CH
#define NNUL 4    // NUM_NULL
#define LOWF 5
#define HIGHF 70
#define S_CHUNK 8
#define WARM 4
#define N_CHUNK 63   // ceil(NT / S_CHUNK)
#define AL 0.35f

__device__ __forceinline__ float dot4(const float4& a, const float4& b) {
    return a.x*b.x + a.y*b.y + a.z*b.z + a.w*b.w;
}
__device__ __forceinline__ float dot8(const float4& a0, const float4& a1,
                                      const float4& b0, const float4& b1) {
    return dot4(a0, b0) + dot4(a1, b1);
}
__device__ __forceinline__ float fast_rcp(float v) {
#if __has_builtin(__builtin_amdgcn_rcpf)
    return __builtin_amdgcn_rcpf(v);
#else
    return 1.0f / v;
#endif
}
__device__ __forceinline__ float fast_sqrt(float v) {
#if __has_builtin(__builtin_amdgcn_sqrtf)
    return __builtin_amdgcn_sqrtf(v);
#else
    return sqrtf(v);
#endif
}
__device__ __forceinline__ float clamp01(float v) {
#if __has_builtin(__builtin_amdgcn_fmed3f)
    return __builtin_amdgcn_fmed3f(v, 0.01f, 1.0f);   // v>=0 here: med3 == clip
#else
    return fminf(fmaxf(v, 0.01f), 1.0f);
#endif
}

// R5 (= R4 resubmit with __has_builtin guards; R4 bench died at container
// level with no GPU data — only compile-risk found was unguarded builtins).
// R4 theory: R2 dataflow (redundant quad loads — R3 proved loads-via-L1 beat
// shuffle reconstruction) + instruction diet + wave rebalance:
//  - marching pointers for x prefetch / outT / s_dcf / s_part (kills per-frame
//    64-bit address recompute chains)
//  - f=256 "extra" path moved from wave 0 (which also owns the wid<5 ratio
//    reduction) to the f=255 quad of wave 15 (tid>=1020): balances the block's
//    critical path into the final barrier; its x row is xpa + (NC - rl),
//    a constant offset — no extra address registers
//  - fast rcp/sqrt/med3 replace IEEE div/sqrt/clamp expansions
//  - pw via quad-neighbor trick: lane n^1's A rows are lane n's B rows, so
//    sq = |A|^2; sq += shfl_xor(sq,1) gives |A|^2+|B|^2 (8 FMA saved)
//  - tr/ti stores predicated: if (n<2) *poT = n==0 ? tr : ti
// Deferred-ratio epilogue (R2) kept: 2 barriers/block.
// launch_bounds(1024,8) pins VGPR<=64 (65+ would halve residency: occupancy
// steps at 64/128). LDS 34KB -> 2 blocks/CU. Grid 504 x 1024.
__global__ __launch_bounds__(1024, 8) void dcf_fused_kernel(
    const float* __restrict__ x,           // (NB,NT,2,NF,NC) fp32
    const int* __restrict__ beam_id,       // (NB,)
    const float* __restrict__ targ_w,      // (8,2,NF,NC) fp32
    const float* __restrict__ null_w,      // (8,NNUL,2,NF,NC) fp32
    float* __restrict__ out)               // fp32: dcf (NB,NT,NF,NNUL) then targ (NB,NT,2,NF)
{
    const int tid = threadIdx.x;
    const int bid = blockIdx.x;
    const int b  = bid & 7;
    const int k  = bid >> 3;
    const int t0 = k * S_CHUNK;
    const int te = min(NT, t0 + S_CHUNK);
    int ts = t0 - WARM; if (ts < 0) ts = 0;

    const int f = tid >> 2;                // 0..255
    const int n = tid & 3;
    const int wid = tid >> 6;
    const int lane = tid & 63;
    const bool extra = (tid >= 1020);      // f=255 quad of wave 15 also does f=256

    __shared__ float s_w256[16 + 4 * 16];       // f=256 weights: twr,twi then per-n nwr,nwi
    __shared__ float s_part[S_CHUNK][25];       // per-frame ratio partials (waves 0..4 write)
    __shared__ float s_dcf[S_CHUNK][1028];      // pre-ratio dcf: [frame][tid], +4 for f=256

    const int beam = beam_id[b];
    const int pA = n & 1;                  // lane's "A" part: 0=real(even n), 1=imag(odd n)
    const int offA = pA * (NF * NC);
    const int offB = (1 - pA) * (NF * NC);
    const int psel = (n == 1 || n == 2) ? 1 : 0;   // targ part for this lane's partial
    const float nsign = pA ? -1.f : 1.f;

    // weights in registers: 6 float4 per thread
    float4 tw0, tw1, nwA0, nwA1, nwB0, nwB1;
    {
        const float* tp = targ_w + ((size_t)(beam * 2 + psel) * NF + f) * NC;
        tw0 = *(const float4*)(tp);  tw1 = *(const float4*)(tp + 4);
        const float* qp = null_w + ((size_t)((beam * NNUL + n) * 2) * NF + f) * NC;
        nwA0 = *(const float4*)(qp + offA);  nwA1 = *(const float4*)(qp + offA + 4);
        nwB0 = *(const float4*)(qp + offB);  nwB1 = *(const float4*)(qp + offB + 4);
    }
    if (tid < 16) {
        int p = tid >> 3, c = tid & 7;
        s_w256[tid] = targ_w[((size_t)(beam * 2 + p) * NF + 256) * NC + c];
    } else if (tid < 80) {
        int i = tid - 16;
        int nn = i >> 4, p = (i >> 3) & 1, c = i & 7;
        s_w256[tid] = null_w[((size_t)((beam * NNUL + nn) * 2 + p) * NF + 256) * NC + c];
    }
    __syncthreads();   // barrier 1 of 2 (weights visible)

    float phi_r = 0.f, phi_i = 0.f, psd = 0.f;
    float phi_r2 = 0.f, phi_i2 = 0.f, psd2 = 0.f;
    const float a = AL, oma = 1.0f - AL;
    const int rl = 2 * NF * NC;            // 4112 floats per (b,t)
    const bool in_red = (f >= LOWF) && (f < HIGHF);   // waves 0..4 only

    // marching pointers (A = lane's parity part, B = other)
    const float* xpa = x + (size_t)(b * NT + ts) * rl + f * NC + offA;
    const float* xpb = x + (size_t)(b * NT + ts) * rl + f * NC + offB;
    float4 pA0 = *(const float4*)(xpa);
    float4 pA1 = *(const float4*)(xpa + 4);
    float4 pB0 = *(const float4*)(xpb);
    float4 pB1 = *(const float4*)(xpb + 4);

    float* outT = out + (size_t)NB * NT * NF * NNUL;
    float* poT = outT + ((size_t)(b * NT + t0) * 2 + n) * NF + f;  // used when n<2
    float* sdp = &s_dcf[0][tid];
    float* spp = &s_part[0][wid * 5];

    for (int t = ts; t < te; ++t) {
        const float4 A0 = pA0, A1 = pA1, B0 = pB0, B1 = pB1;
        xpa += rl; xpb += rl;
        if (t + 1 < te) {
            pA0 = *(const float4*)(xpa);
            pA1 = *(const float4*)(xpa + 4);
            pB0 = *(const float4*)(xpb);
            pB1 = *(const float4*)(xpb + 4);
        }

        // targ dots via quad butterfly: lane n's partial d covers
        // n0: xr.twr  n1: xi.twi  n2: xr.twi  n3: xi.twr
        const float d = dot8(A0, A1, tw0, tw1);
        const float e = __shfl_xor(d, 1);
        const float u = (n < 2) ? ((n == 0) ? (d - e) : (e - d)) : (d + e);
        const float v = __shfl_xor(u, 2);
        const float tr = (n < 2) ? u : v;
        const float ti = (n < 2) ? v : u;

        // null dots (select-free via A/B address swap; nr needs one sign)
        const float P = dot8(A0, A1, nwA0, nwA1);
        const float Q = dot8(B0, B1, nwB0, nwB1);
        const float nr = nsign * (P - Q);
        const float ni = dot8(A0, A1, nwB0, nwB1) + dot8(B0, B1, nwA0, nwA1);

        // pw: |A|^2 here; quad-neighbor (n^1) holds |B|^2 in its sq
        float sq = dot4(A0, A0) + dot4(A1, A1);
        sq += __shfl_xor(sq, 1);
        const float pw = sq * 0.125f;

        if (t == 0) {  // exact asymmetric init from the reference
            phi_r = oma * tr * nr + ti * ni;
            phi_i = oma * ti * nr - tr * ni;
            psd   = oma * pw;
        } else {
            phi_r = a * phi_r + oma * (tr * nr + ti * ni);
            phi_i = a * phi_i + oma * (ti * nr - tr * ni);
            psd   = a * psd + oma * pw;
        }

        // f=256 on the f=255 quad of wave 15: weights from LDS,
        // x row = current frame's f=255 row + NC (pointers already advanced)
        float tr2 = 0.f, ti2 = 0.f;
        if (extra) {
            const float* xe  = xpa + (NC - rl);
            const float* xe2 = xpb + (NC - rl);
            const float4 eA0 = *(const float4*)(xe);
            const float4 eA1 = *(const float4*)(xe + 4);
            const float4 eB0 = *(const float4*)(xe2);
            const float4 eB1 = *(const float4*)(xe2 + 4);
            const float4 etw0 = *(const float4*)&s_w256[psel * 8];
            const float4 etw1 = *(const float4*)&s_w256[psel * 8 + 4];
            const float* nq = &s_w256[16 + n * 16];
            const float4 enA0 = *(const float4*)(nq + pA * 8);
            const float4 enA1 = *(const float4*)(nq + pA * 8 + 4);
            const float4 enB0 = *(const float4*)(nq + (1 - pA) * 8);
            const float4 enB1 = *(const float4*)(nq + (1 - pA) * 8 + 4);
            const float d2 = dot8(eA0, eA1, etw0, etw1);
            const float e2 = __shfl_xor(d2, 1);
            const float u2 = (n < 2) ? ((n == 0) ? (d2 - e2) : (e2 - d2)) : (d2 + e2);
            const float v2 = __shfl_xor(u2, 2);
            tr2 = (n < 2) ? u2 : v2;
            ti2 = (n < 2) ? v2 : u2;
            const float P2 = dot8(eA0, eA1, enA0, enA1);
            const float Q2 = dot8(eB0, eB1, enB0, enB1);
            const float nr2 = nsign * (P2 - Q2);
            const float ni2 = dot8(eA0, eA1, enB0, enB1) + dot8(eB0, eB1, enA0, enA1);
            float sq2 = dot4(eA0, eA0) + dot4(eA1, eA1);
            sq2 += __shfl_xor(sq2, 1);
            const float pw2 = sq2 * 0.125f;
            if (t == 0) {
                phi_r2 = oma * tr2 * nr2 + ti2 * ni2;
                phi_i2 = oma * ti2 * nr2 - tr2 * ni2;
                psd2   = oma * pw2;
            } else {
                phi_r2 = a * phi_r2 + oma * (tr2 * nr2 + ti2 * ni2);
                phi_i2 = a * phi_i2 + oma * (ti2 * nr2 - tr2 * ni2);
                psd2   = a * psd2 + oma * pw2;
            }
        }

        if (t >= t0) {
            const float phi = fast_sqrt(phi_r * phi_r + phi_i * phi_i);
            const float dcfv = clamp01(phi * fast_rcp(psd + 1e-13f));
            if (n < 2) *poT = (n == 0) ? tr : ti;
            *sdp = dcfv;                                 // pre-ratio, own slot
            if (extra) {
                const float phi2 = fast_sqrt(phi_r2 * phi_r2 + phi_i2 * phi_i2);
                const float dcf2v = clamp01(phi2 * fast_rcp(psd2 + 1e-13f));
                sdp[4] = dcf2v;                          // slot 1024+n (tid=1020+n)
                if (n < 2) poT[1] = (n == 0) ? tr2 : ti2;   // f=256 targ
            }
            // ratio partials: waves 0..4 hold f in [5,70); NO barrier here
            if (wid < 5) {
                float v_phi = in_red ? phi : 0.f;
                float v_psd = (in_red && n == 0) ? psd : 0.f;
                #pragma unroll
                for (int off = 4; off < 64; off <<= 1) {
                    v_phi += __shfl_xor(v_phi, off);
                    v_psd += __shfl_xor(v_psd, off);
                }
                if (lane < 4)  spp[lane] = v_phi;        // phi sum, n=lane
                if (lane == 0) spp[4]    = v_psd;        // psd sum
            }
            poT += 2 * NF; sdp += 1028; spp += 25;
        }
    }

    __syncthreads();   // barrier 2 of 2: all frames' s_dcf + s_part visible

    // uniform epilogue: apply ratio, write final dcf for all output frames
    float* po = out + ((size_t)(b * NT + t0) * NF + f) * NNUL + n;
    const float* sdr = &s_dcf[0][tid];
    const float* spr = &s_part[0][0];
    const int nf = te - t0;
    for (int fr = 0; fr < nf; ++fr) {
        const int t = t0 + fr;
        float dcfv = sdr[0];
        float dcf2v = extra ? sdr[4] : 0.f;
        if (t >= 1) {
            const float pre = spr[4] + spr[9] + spr[14] + spr[19] + spr[24];
            const float aft = spr[n] + spr[5 + n] + spr[10 + n] + spr[15 + n] + spr[20 + n];
            const float ratio = clamp01(aft * fast_rcp(pre + 1e-10f));
            dcfv = fast_sqrt(dcfv * ratio);
            if (extra) dcf2v = fast_sqrt(dcf2v * ratio);
        }
        *po = dcfv;
        if (extra) po[NNUL] = dcf2v;                     // f=256 slot
        po += NF * NNUL; sdr += 1028; spr += 25;
    }
}

extern "C" void kernel_launch(void* const* d_in, const int* in_sizes, int n_in,
                              void* d_out, int out_size, void* d_ws, size_t ws_size,
                              hipStream_t stream) {
    const float* x       = (const float*)d_in[0];
    const int*   beam_id = (const int*)d_in[1];
    const float* targ_w  = (const float*)d_in[2];
    const float* null_w  = (const float*)d_in[3];
    float* out           = (float*)d_out;
    (void)d_ws; (void)ws_size;

    dcf_fused_kernel<<<dim3(NB * N_CHUNK), dim3(1024), 0, stream>>>(
        x, beam_id, targ_w, null_w, out);
}

// Round 6
// 130.389 us; speedup vs baseline: 2.9360x; 2.9360x over previous
//
#include <hip/hip_runtime.h>

#define NB 8      // NUM_BLOCK
#define NT 500    // NUM_FRAME
#define NF 257    // NUM_BIN
#define NC 8      // NUM_CH
#define NNUL 4    // NUM_NULL
#define LOWF 5
#define HIGHF 70
#define S_CHUNK 8
#define WARM 4
#define N_CHUNK 63   // ceil(NT / S_CHUNK)
#define AL 0.35f

__device__ __forceinline__ float dot4(const float4& a, const float4& b) {
    return a.x*b.x + a.y*b.y + a.z*b.z + a.w*b.w;
}
__device__ __forceinline__ float dot8(const float4& a0, const float4& a1,
                                      const float4& b0, const float4& b1) {
    return dot4(a0, b0) + dot4(a1, b1);
}
__device__ __forceinline__ float fast_rcp(float v) {
#if __has_builtin(__builtin_amdgcn_rcpf)
    return __builtin_amdgcn_rcpf(v);
#else
    return 1.0f / v;
#endif
}
__device__ __forceinline__ float fast_sqrt(float v) {
#if __has_builtin(__builtin_amdgcn_sqrtf)
    return __builtin_amdgcn_sqrtf(v);
#else
    return sqrtf(v);
#endif
}
__device__ __forceinline__ float clamp01(float v) {
#if __has_builtin(__builtin_amdgcn_fmed3f)
    return __builtin_amdgcn_fmed3f(v, 0.01f, 1.0f);   // v>=0 here: med3 == clip
#else
    return fminf(fmaxf(v, 0.01f), 1.0f);
#endif
}

// R6 = R5 with launch_bounds reverted (1024,8)->(1024,4).
// R5 POST-MORTEM: (1024,8) forced a 32-VGPR budget on a ~60-VGPR body ->
// full spill to scratch: WRITE_SIZE 24MB->563MB, FETCH 37->434MB, 306us.
// LESSON (do not retry): this 1024-thread body needs the (1024,4) cap
// (VGPR<=128, compiler lands at ~60, zero spill). Occupancy is LDS-bound
// (34KB -> 2 blocks/CU) anyway, so the tighter reg cap bought nothing.
// Kept from R4/R5 (instruction diet on the proven R2 dataflow; R3 proved
// redundant quad loads via L1 beat shuffle reconstruction):
//  - marching pointers for x prefetch / outT / s_dcf / s_part
//  - f=256 "extra" path on the f=255 quad of wave 15 (tid>=1020), off the
//    ratio-reduction waves (wid<5); its x row is xpa + (NC - rl)
//  - fast rcp/sqrt/med3 replace IEEE div/sqrt/clamp expansions
//  - pw via quad-neighbor trick: sq=|A|^2; sq+=shfl_xor(sq,1) -> |A|^2+|B|^2
//  - tr/ti stores predicated on n<2
// Deferred-ratio epilogue (R2): 2 barriers/block total.
__global__ __launch_bounds__(1024, 4) void dcf_fused_kernel(
    const float* __restrict__ x,           // (NB,NT,2,NF,NC) fp32
    const int* __restrict__ beam_id,       // (NB,)
    const float* __restrict__ targ_w,      // (8,2,NF,NC) fp32
    const float* __restrict__ null_w,      // (8,NNUL,2,NF,NC) fp32
    float* __restrict__ out)               // fp32: dcf (NB,NT,NF,NNUL) then targ (NB,NT,2,NF)
{
    const int tid = threadIdx.x;
    const int bid = blockIdx.x;
    const int b  = bid & 7;
    const int k  = bid >> 3;
    const int t0 = k * S_CHUNK;
    const int te = min(NT, t0 + S_CHUNK);
    int ts = t0 - WARM; if (ts < 0) ts = 0;

    const int f = tid >> 2;                // 0..255
    const int n = tid & 3;
    const int wid = tid >> 6;
    const int lane = tid & 63;
    const bool extra = (tid >= 1020);      // f=255 quad of wave 15 also does f=256

    __shared__ float s_w256[16 + 4 * 16];       // f=256 weights: twr,twi then per-n nwr,nwi
    __shared__ float s_part[S_CHUNK][25];       // per-frame ratio partials (waves 0..4 write)
    __shared__ float s_dcf[S_CHUNK][1028];      // pre-ratio dcf: [frame][tid], +4 for f=256

    const int beam = beam_id[b];
    const int pA = n & 1;                  // lane's "A" part: 0=real(even n), 1=imag(odd n)
    const int offA = pA * (NF * NC);
    const int offB = (1 - pA) * (NF * NC);
    const int psel = (n == 1 || n == 2) ? 1 : 0;   // targ part for this lane's partial
    const float nsign = pA ? -1.f : 1.f;

    // weights in registers: 6 float4 per thread
    float4 tw0, tw1, nwA0, nwA1, nwB0, nwB1;
    {
        const float* tp = targ_w + ((size_t)(beam * 2 + psel) * NF + f) * NC;
        tw0 = *(const float4*)(tp);  tw1 = *(const float4*)(tp + 4);
        const float* qp = null_w + ((size_t)((beam * NNUL + n) * 2) * NF + f) * NC;
        nwA0 = *(const float4*)(qp + offA);  nwA1 = *(const float4*)(qp + offA + 4);
        nwB0 = *(const float4*)(qp + offB);  nwB1 = *(const float4*)(qp + offB + 4);
    }
    if (tid < 16) {
        int p = tid >> 3, c = tid & 7;
        s_w256[tid] = targ_w[((size_t)(beam * 2 + p) * NF + 256) * NC + c];
    } else if (tid < 80) {
        int i = tid - 16;
        int nn = i >> 4, p = (i >> 3) & 1, c = i & 7;
        s_w256[tid] = null_w[((size_t)((beam * NNUL + nn) * 2 + p) * NF + 256) * NC + c];
    }
    __syncthreads();   // barrier 1 of 2 (weights visible)

    float phi_r = 0.f, phi_i = 0.f, psd = 0.f;
    float phi_r2 = 0.f, phi_i2 = 0.f, psd2 = 0.f;
    const float a = AL, oma = 1.0f - AL;
    const int rl = 2 * NF * NC;            // 4112 floats per (b,t)
    const bool in_red = (f >= LOWF) && (f < HIGHF);   // waves 0..4 only

    // marching pointers (A = lane's parity part, B = other)
    const float* xpa = x + (size_t)(b * NT + ts) * rl + f * NC + offA;
    const float* xpb = x + (size_t)(b * NT + ts) * rl + f * NC + offB;
    float4 pA0 = *(const float4*)(xpa);
    float4 pA1 = *(const float4*)(xpa + 4);
    float4 pB0 = *(const float4*)(xpb);
    float4 pB1 = *(const float4*)(xpb + 4);

    float* outT = out + (size_t)NB * NT * NF * NNUL;
    float* poT = outT + ((size_t)(b * NT + t0) * 2 + n) * NF + f;  // used when n<2
    float* sdp = &s_dcf[0][tid];
    float* spp = &s_part[0][wid * 5];

    for (int t = ts; t < te; ++t) {
        const float4 A0 = pA0, A1 = pA1, B0 = pB0, B1 = pB1;
        xpa += rl; xpb += rl;
        if (t + 1 < te) {
            pA0 = *(const float4*)(xpa);
            pA1 = *(const float4*)(xpa + 4);
            pB0 = *(const float4*)(xpb);
            pB1 = *(const float4*)(xpb + 4);
        }

        // targ dots via quad butterfly: lane n's partial d covers
        // n0: xr.twr  n1: xi.twi  n2: xr.twi  n3: xi.twr
        const float d = dot8(A0, A1, tw0, tw1);
        const float e = __shfl_xor(d, 1);
        const float u = (n < 2) ? ((n == 0) ? (d - e) : (e - d)) : (d + e);
        const float v = __shfl_xor(u, 2);
        const float tr = (n < 2) ? u : v;
        const float ti = (n < 2) ? v : u;

        // null dots (select-free via A/B address swap; nr needs one sign)
        const float P = dot8(A0, A1, nwA0, nwA1);
        const float Q = dot8(B0, B1, nwB0, nwB1);
        const float nr = nsign * (P - Q);
        const float ni = dot8(A0, A1, nwB0, nwB1) + dot8(B0, B1, nwA0, nwA1);

        // pw: |A|^2 here; quad-neighbor (n^1) holds |B|^2 in its sq
        float sq = dot4(A0, A0) + dot4(A1, A1);
        sq += __shfl_xor(sq, 1);
        const float pw = sq * 0.125f;

        if (t == 0) {  // exact asymmetric init from the reference
            phi_r = oma * tr * nr + ti * ni;
            phi_i = oma * ti * nr - tr * ni;
            psd   = oma * pw;
        } else {
            phi_r = a * phi_r + oma * (tr * nr + ti * ni);
            phi_i = a * phi_i + oma * (ti * nr - tr * ni);
            psd   = a * psd + oma * pw;
        }

        // f=256 on the f=255 quad of wave 15: weights from LDS,
        // x row = current frame's f=255 row + NC (pointers already advanced)
        float tr2 = 0.f, ti2 = 0.f;
        if (extra) {
            const float* xe  = xpa + (NC - rl);
            const float* xe2 = xpb + (NC - rl);
            const float4 eA0 = *(const float4*)(xe);
            const float4 eA1 = *(const float4*)(xe + 4);
            const float4 eB0 = *(const float4*)(xe2);
            const float4 eB1 = *(const float4*)(xe2 + 4);
            const float4 etw0 = *(const float4*)&s_w256[psel * 8];
            const float4 etw1 = *(const float4*)&s_w256[psel * 8 + 4];
            const float* nq = &s_w256[16 + n * 16];
            const float4 enA0 = *(const float4*)(nq + pA * 8);
            const float4 enA1 = *(const float4*)(nq + pA * 8 + 4);
            const float4 enB0 = *(const float4*)(nq + (1 - pA) * 8);
            const float4 enB1 = *(const float4*)(nq + (1 - pA) * 8 + 4);
            const float d2 = dot8(eA0, eA1, etw0, etw1);
            const float e2 = __shfl_xor(d2, 1);
            const float u2 = (n < 2) ? ((n == 0) ? (d2 - e2) : (e2 - d2)) : (d2 + e2);
            const float v2 = __shfl_xor(u2, 2);
            tr2 = (n < 2) ? u2 : v2;
            ti2 = (n < 2) ? v2 : u2;
            const float P2 = dot8(eA0, eA1, enA0, enA1);
            const float Q2 = dot8(eB0, eB1, enB0, enB1);
            const float nr2 = nsign * (P2 - Q2);
            const float ni2 = dot8(eA0, eA1, enB0, enB1) + dot8(eB0, eB1, enA0, enA1);
            float sq2 = dot4(eA0, eA0) + dot4(eA1, eA1);
            sq2 += __shfl_xor(sq2, 1);
            const float pw2 = sq2 * 0.125f;
            if (t == 0) {
                phi_r2 = oma * tr2 * nr2 + ti2 * ni2;
                phi_i2 = oma * ti2 * nr2 - tr2 * ni2;
                psd2   = oma * pw2;
            } else {
                phi_r2 = a * phi_r2 + oma * (tr2 * nr2 + ti2 * ni2);
                phi_i2 = a * phi_i2 + oma * (ti2 * nr2 - tr2 * ni2);
                psd2   = a * psd2 + oma * pw2;
            }
        }

        if (t >= t0) {
            const float phi = fast_sqrt(phi_r * phi_r + phi_i * phi_i);
            const float dcfv = clamp01(phi * fast_rcp(psd + 1e-13f));
            if (n < 2) *poT = (n == 0) ? tr : ti;
            *sdp = dcfv;                                 // pre-ratio, own slot
            if (extra) {
                const float phi2 = fast_sqrt(phi_r2 * phi_r2 + phi_i2 * phi_i2);
                const float dcf2v = clamp01(phi2 * fast_rcp(psd2 + 1e-13f));
                sdp[4] = dcf2v;                          // slot 1024+n (tid=1020+n)
                if (n < 2) poT[1] = (n == 0) ? tr2 : ti2;   // f=256 targ
            }
            // ratio partials: waves 0..4 hold f in [5,70); NO barrier here
            if (wid < 5) {
                float v_phi = in_red ? phi : 0.f;
                float v_psd = (in_red && n == 0) ? psd : 0.f;
                #pragma unroll
                for (int off = 4; off < 64; off <<= 1) {
                    v_phi += __shfl_xor(v_phi, off);
                    v_psd += __shfl_xor(v_psd, off);
                }
                if (lane < 4)  spp[lane] = v_phi;        // phi sum, n=lane
                if (lane == 0) spp[4]    = v_psd;        // psd sum
            }
            poT += 2 * NF; sdp += 1028; spp += 25;
        }
    }

    __syncthreads();   // barrier 2 of 2: all frames' s_dcf + s_part visible

    // uniform epilogue: apply ratio, write final dcf for all output frames
    float* po = out + ((size_t)(b * NT + t0) * NF + f) * NNUL + n;
    const float* sdr = &s_dcf[0][tid];
    const float* spr = &s_part[0][0];
    const int nf = te - t0;
    for (int fr = 0; fr < nf; ++fr) {
        const int t = t0 + fr;
        float dcfv = sdr[0];
        float dcf2v = extra ? sdr[4] : 0.f;
        if (t >= 1) {
            const float pre = spr[4] + spr[9] + spr[14] + spr[19] + spr[24];
            const float aft = spr[n] + spr[5 + n] + spr[10 + n] + spr[15 + n] + spr[20 + n];
            const float ratio = clamp01(aft * fast_rcp(pre + 1e-10f));
            dcfv = fast_sqrt(dcfv * ratio);
            if (extra) dcf2v = fast_sqrt(dcf2v * ratio);
        }
        *po = dcfv;
        if (extra) po[NNUL] = dcf2v;                     // f=256 slot
        po += NF * NNUL; sdr += 1028; spr += 25;
    }
}

extern "C" void kernel_launch(void* const* d_in, const int* in_sizes, int n_in,
                              void* d_out, int out_size, void* d_ws, size_t ws_size,
                              hipStream_t stream) {
    const float* x       = (const float*)d_in[0];
    const int*   beam_id = (const int*)d_in[1];
    const float* targ_w  = (const float*)d_in[2];
    const float* null_w  = (const float*)d_in[3];
    float* out           = (float*)d_out;
    (void)d_ws; (void)ws_size;

    dcf_fused_kernel<<<dim3(NB * N_CHUNK), dim3(1024), 0, stream>>>(
        x, beam_id, targ_w, null_w, out);
}